// Round 2
// baseline (366.244 us; speedup 1.0000x reference)
//
#include <hip/hip_runtime.h>
#include <hip/hip_bf16.h>
#include <stdint.h>

// B=2, T=2048, D=1024, H=16, HD=64, SCALE=1/8. Softmax is over the HEAD axis.
typedef __bf16 bf16;
typedef __attribute__((ext_vector_type(8))) __bf16 bf16x8;
typedef __attribute__((ext_vector_type(2))) __bf16 bf16x2;
typedef __attribute__((ext_vector_type(4))) float f32x4;

#define MFMA_16x16x32(a, b, c) __builtin_amdgcn_mfma_f32_16x16x32_bf16((a), (b), (c), 0, 0, 0)

__device__ __forceinline__ void gld_lds16(const void* g, void* l) {
    __builtin_amdgcn_global_load_lds(
        (const __attribute__((address_space(1))) void*)g,
        (__attribute__((address_space(3))) void*)l,
        16, 0, 0);
}

// ---------- fp32 -> bf16 convert (vectorized) ----------
__global__ void cvt_f32_bf16(const float* __restrict__ in, bf16* __restrict__ out, int n) {
    int i = (blockIdx.x * blockDim.x + threadIdx.x) * 8;
    if (i >= n) return;
    f32x4 a = *(const f32x4*)(in + i);
    f32x4 b = *(const f32x4*)(in + i + 4);
    bf16x8 o;
#pragma unroll
    for (int j = 0; j < 4; ++j) { o[j] = (bf16)a[j]; o[j + 4] = (bf16)b[j]; }
    *(bf16x8*)(out + i) = o;
}

// ---------- transpose + convert: in[R][C] f32 -> out[C][R] bf16 ----------
__global__ void transpose_cvt(const float* __restrict__ in, bf16* __restrict__ out, int R, int C) {
    __shared__ float tile[32][33];
    int c0 = blockIdx.x * 32, r0 = blockIdx.y * 32;
    int tc = threadIdx.x & 31, tr = threadIdx.x >> 5; // tr in 0..7
#pragma unroll
    for (int i = 0; i < 4; ++i) {
        int r = tr + i * 8;
        tile[r][tc] = in[(size_t)(r0 + r) * C + c0 + tc];
    }
    __syncthreads();
#pragma unroll
    for (int i = 0; i < 4; ++i) {
        int r = tr + i * 8; // out row = original column
        out[(size_t)(c0 + r) * R + r0 + tc] = (bf16)tile[tc][r];
    }
}

// ---------- bf16 GEMM, C = A[M,K] @ Bt[N,K]^T ; 128x128 tile, BK=32, 4 waves ----------
template <int EPI>
__global__ void __launch_bounds__(256) gemm_bf16(
    const bf16* __restrict__ A, const bf16* __restrict__ Bt, int M, int N, int K,
    float* __restrict__ Cf, const float* __restrict__ bias,
    bf16* __restrict__ q_out, bf16* __restrict__ k_out, bf16* __restrict__ v_out)
{
    __shared__ bf16 As[128 * 32];
    __shared__ bf16 Bs[128 * 32];
    const int t = threadIdx.x, w = t >> 6, l = t & 63;
    const int l15 = l & 15, lh = l >> 4;
    const int m0 = blockIdx.y * 128, n0 = blockIdx.x * 128;
    const int wm = w >> 1, wn = w & 1;

    const int srow = w * 16 + (l >> 2);
    const int scol = (l & 3) * 8;
    const bf16* gA = A + (size_t)(m0 + srow) * K + scol;
    const bf16* gB = Bt + (size_t)(n0 + srow) * K + scol;
    char* lA = (char*)As + w * 1024;
    char* lB = (char*)Bs + w * 1024;

    f32x4 acc[4][4] = {};

    for (int kt = 0; kt < K; kt += 32) {
        __syncthreads();
        gld_lds16(gA + kt, lA);
        gld_lds16(gA + (size_t)64 * K + kt, lA + 4096);
        gld_lds16(gB + kt, lB);
        gld_lds16(gB + (size_t)64 * K + kt, lB + 4096);
        asm volatile("s_waitcnt vmcnt(0)" ::: "memory");
        __syncthreads();

        const bf16* pa = As + (wm * 64 + l15) * 32 + lh * 8;
        const bf16* pb = Bs + (wn * 64 + l15) * 32 + lh * 8;
        bf16x8 af[4], bfr[4];
#pragma unroll
        for (int i = 0; i < 4; ++i) {
            af[i]  = *(const bf16x8*)(pa + i * 512);
            bfr[i] = *(const bf16x8*)(pb + i * 512);
        }
#pragma unroll
        for (int mi = 0; mi < 4; ++mi)
#pragma unroll
            for (int ni = 0; ni < 4; ++ni)
                acc[mi][ni] = MFMA_16x16x32(af[mi], bfr[ni], acc[mi][ni]);
    }

    if (EPI == 1) {
#pragma unroll
        for (int ni = 0; ni < 4; ++ni) {
            int n = n0 + wn * 64 + ni * 16 + l15;
            float bb = bias[n];
#pragma unroll
            for (int mi = 0; mi < 4; ++mi)
#pragma unroll
                for (int r = 0; r < 4; ++r) {
                    int m = m0 + wm * 64 + mi * 16 + lh * 4 + r;
                    Cf[(size_t)m * N + n] = acc[mi][ni][r] + bb;
                }
        }
    } else {
        const int which = n0 >> 10; // 0:q 1:k 2:v — uniform per block
#pragma unroll
        for (int ni = 0; ni < 4; ++ni) {
            int n = n0 + wn * 64 + ni * 16 + l15;
            int h = (n >> 6) & 15;
            int d = n & 63;
#pragma unroll
            for (int mi = 0; mi < 4; ++mi)
#pragma unroll
                for (int r = 0; r < 4; ++r) {
                    int m = m0 + wm * 64 + mi * 16 + lh * 4 + r;
                    int b = m >> 11, tt = m & 2047;
                    bf16 val = (bf16)acc[mi][ni][r];
                    size_t hb = (size_t)b * 16 + h;
                    if (which == 0)      q_out[(hb * 2048 + tt) * 64 + d] = val;
                    else if (which == 1) k_out[(hb * 2048 + tt) * 64 + d] = val;
                    else                 v_out[(hb * 64 + d) * 2048 + tt] = val;
                }
        }
    }
}

// ---------- attention with head-axis softmax, v2 ----------
// grid 512: bid&7 -> (b, kslice) so each XCD owns one 4MB K/V slice (L2-resident);
// bid>>3 -> qtile (64). 1024 threads = 16 waves, wave w = head w. 2 blocks/CU.
// exp2 is applied in the score phase (in-register, per-wave); the softmax phase
// only computes per-(q,k) column sums over heads -> invS; PV multiplies e*inv.
__global__ void __launch_bounds__(1024, 8) attn_kernel(
    const bf16* __restrict__ Q, const bf16* __restrict__ Kmat, const bf16* __restrict__ Vt,
    bf16* __restrict__ p0, bf16* __restrict__ p1, bf16* __restrict__ p2, bf16* __restrict__ p3)
{
    __shared__ bf16 S[16][32][40];  // exp2'd scores e[h][q][k], padded
    __shared__ bf16 invS[32][40];   // 1/sum_h e at each (q,k)
    const int t = threadIdx.x;
    const int w = t >> 6;       // head
    const int l = t & 63;
    const int l15 = l & 15, lh = l >> 4;

    const int bid = blockIdx.x;
    const int b = (bid & 7) >> 2;
    const int ks = bid & 3;
    const int qt = (bid >> 3) * 32;

    const size_t headQK = ((size_t)b * 16 + w) * (2048 * 64); // [B,H,T,HD]
    const size_t headV  = ((size_t)b * 16 + w) * (64 * 2048); // [B,H,HD,T]
    const float SCL = 0.125f * 1.44269504089f; // scale * log2(e)

    // Q fragments live in registers for the whole block
    bf16x8 aq[2][2];
#pragma unroll
    for (int qb2 = 0; qb2 < 2; ++qb2)
#pragma unroll
        for (int ds = 0; ds < 2; ++ds)
            aq[qb2][ds] = *(const bf16x8*)(Q + headQK + (size_t)(qt + qb2 * 16 + l15) * 64 + ds * 32 + lh * 8);

    f32x4 o[2][4] = {};

    for (int it = 0; it < 16; ++it) {
        const int kt = ks * 512 + it * 32;
        // hoist K loads above barrier: latency hides under barrier wait
        bf16x8 bk0[2], bk1[2];
#pragma unroll
        for (int kb = 0; kb < 2; ++kb) {
            const bf16* kp = Kmat + headQK + (size_t)(kt + kb * 16 + l15) * 64 + lh * 8;
            bk0[kb] = *(const bf16x8*)(kp);
            bk1[kb] = *(const bf16x8*)(kp + 32);
        }
        __syncthreads(); // previous iteration's PV done reading S/invS
        // --- scores -> e = exp2(s*SCL), stored bf16 (softmax-over-heads numerator) ---
#pragma unroll
        for (int kb = 0; kb < 2; ++kb) {
#pragma unroll
            for (int qb2 = 0; qb2 < 2; ++qb2) {
                f32x4 s = {};
                s = MFMA_16x16x32(aq[qb2][0], bk0[kb], s);
                s = MFMA_16x16x32(aq[qb2][1], bk1[kb], s);
#pragma unroll
                for (int r = 0; r < 4; ++r)
                    S[w][qb2 * 16 + lh * 4 + r][kb * 16 + l15] = (bf16)exp2f(s[r] * SCL);
            }
        }
        __syncthreads();
        // --- column sums over heads (waves 0..7 only; 2 columns per thread) ---
        if (t < 512) {
            const int sqi = t >> 4, skc = (t & 15) * 2;
            float s0 = 0.f, s1 = 0.f;
#pragma unroll
            for (int hh = 0; hh < 16; ++hh) {
                bf16x2 pr = *(const bf16x2*)&S[hh][sqi][skc];
                s0 += (float)pr[0];
                s1 += (float)pr[1];
            }
            bf16x2 iv;
            iv[0] = (bf16)__builtin_amdgcn_rcpf(s0);
            iv[1] = (bf16)__builtin_amdgcn_rcpf(s1);
            *(bf16x2*)&invS[sqi][skc] = iv;
        }
        __syncthreads();
        // --- PV: o += (e * inv) @ V ---
        bf16x8 bv[4];
#pragma unroll
        for (int ni = 0; ni < 4; ++ni)
            bv[ni] = *(const bf16x8*)(Vt + headV + (size_t)(ni * 16 + l15) * 2048 + kt + lh * 8);
#pragma unroll
        for (int qb2 = 0; qb2 < 2; ++qb2) {
            bf16x8 ev  = *(const bf16x8*)(&S[w][qb2 * 16 + l15][lh * 8]);
            bf16x8 ivv = *(const bf16x8*)(&invS[qb2 * 16 + l15][lh * 8]);
            bf16x8 ap;
#pragma unroll
            for (int j = 0; j < 8; ++j)
                ap[j] = (bf16)((float)ev[j] * (float)ivv[j]);
#pragma unroll
            for (int ni = 0; ni < 4; ++ni)
                o[qb2][ni] = MFMA_16x16x32(ap, bv[ni], o[qb2][ni]);
        }
    }
    // write this k-slice's partial: slice[ks] layout [b][t][h*64+d]
    bf16* dst = (ks == 0 ? p0 : ks == 1 ? p1 : ks == 2 ? p2 : p3) + (size_t)b * (2048 * 1024);
#pragma unroll
    for (int qb2 = 0; qb2 < 2; ++qb2)
#pragma unroll
        for (int ni = 0; ni < 4; ++ni)
#pragma unroll
            for (int r = 0; r < 4; ++r) {
                int tt = qt + qb2 * 16 + lh * 4 + r;
                int d = ni * 16 + l15;
                dst[(size_t)tt * 1024 + w * 64 + d] = (bf16)o[qb2][ni][r];
            }
}

// ---------- sum the four k-slice partials -> attn bf16 (in-place onto p0 region) ----------
__global__ void reduce_part4(const bf16* __restrict__ p0, const bf16* __restrict__ p1,
                             const bf16* __restrict__ p2, const bf16* __restrict__ p3,
                             bf16* __restrict__ out, int n) {
    int i = (blockIdx.x * blockDim.x + threadIdx.x) * 8;
    if (i >= n) return;
    bf16x8 a = *(const bf16x8*)(p0 + i);
    bf16x8 b = *(const bf16x8*)(p1 + i);
    bf16x8 c = *(const bf16x8*)(p2 + i);
    bf16x8 d = *(const bf16x8*)(p3 + i);
    bf16x8 o;
#pragma unroll
    for (int j = 0; j < 8; ++j)
        o[j] = (bf16)(((float)a[j] + (float)b[j]) + ((float)c[j] + (float)d[j]));
    *(bf16x8*)(out + i) = o;
}

extern "C" void kernel_launch(void* const* d_in, const int* in_sizes, int n_in,
                              void* d_out, int out_size, void* d_ws, size_t ws_size,
                              hipStream_t stream)
{
    const float* x      = (const float*)d_in[0];
    const float* w_qkv  = (const float*)d_in[1];
    const float* w_proj = (const float*)d_in[2];
    const float* b_proj = (const float*)d_in[3];
    float* out = (float*)d_out;

    // workspace layout (58 MiB; part slices overlap regions dead after gemm1)
    char* ws = (char*)d_ws;
    const size_t MB = 1048576;
    bf16* wprojT = (bf16*)(ws + 0 * MB);   //  2 MiB  w_proj^T bf16 [1024,1024]
    bf16* xb     = (bf16*)(ws + 2 * MB);   //  8 MiB  x bf16 [4096,1024]   (later: part0 / attnb)
    bf16* wqkvT  = (bf16*)(ws + 10 * MB);  //  6 MiB  w_qkv^T bf16 [3072,1024] (later: part1)
    bf16* qb     = (bf16*)(ws + 18 * MB);  //  8 MiB  Q  [B,H,T,HD]
    bf16* kb     = (bf16*)(ws + 26 * MB);  //  8 MiB  K  [B,H,T,HD]
    bf16* vt     = (bf16*)(ws + 34 * MB);  //  8 MiB  V^T[B,H,HD,T]
    bf16* part0  = (bf16*)(ws + 2 * MB);   //  8 MiB  (over xb, dead after gemm1)
    bf16* part1  = (bf16*)(ws + 10 * MB);  //  8 MiB  (over wqkvT)
    bf16* part2  = (bf16*)(ws + 42 * MB);  //  8 MiB
    bf16* part3  = (bf16*)(ws + 50 * MB);  //  8 MiB
    bf16* attnb  = (bf16*)(ws + 2 * MB);   //  8 MiB  = part0 (element-wise in-place reduce)

    cvt_f32_bf16<<<2048, 256, 0, stream>>>(x, xb, 4194304);
    transpose_cvt<<<dim3(96, 32), 256, 0, stream>>>(w_qkv, wqkvT, 1024, 3072);
    transpose_cvt<<<dim3(32, 32), 256, 0, stream>>>(w_proj, wprojT, 1024, 1024);

    // qkv projection: [4096,1024] @ [1024,3072] -> scatter to q/k/v^T
    gemm_bf16<0><<<dim3(24, 32), 256, 0, stream>>>(xb, wqkvT, 4096, 3072, 1024,
                                                   nullptr, nullptr, qb, kb, vt);
    // attention with head-axis softmax (4 k-slices, XCD-grouped)
    attn_kernel<<<512, 1024, 0, stream>>>(qb, kb, vt, part0, part1, part2, part3);
    reduce_part4<<<2048, 256, 0, stream>>>(part0, part1, part2, part3, attnb, 4194304);
    // output projection + bias -> fp32 d_out
    gemm_bf16<1><<<dim3(8, 32), 256, 0, stream>>>(attnb, wprojT, 4096, 1024, 1024,
                                                  out, b_proj, nullptr, nullptr, nullptr);

    (void)in_sizes; (void)n_in; (void)out_size; (void)ws_size;
}

// Round 3
// 329.160 us; speedup vs baseline: 1.1127x; 1.1127x over previous
//
#include <hip/hip_runtime.h>
#include <hip/hip_bf16.h>
#include <stdint.h>

// B=2, T=2048, D=1024, H=16, HD=64, SCALE=1/8. Softmax is over the HEAD axis.
typedef __bf16 bf16;
typedef __attribute__((ext_vector_type(8))) __bf16 bf16x8;
typedef __attribute__((ext_vector_type(2))) __bf16 bf16x2;
typedef __attribute__((ext_vector_type(4))) float f32x4;

#define MFMA_16x16x32(a, b, c) __builtin_amdgcn_mfma_f32_16x16x32_bf16((a), (b), (c), 0, 0, 0)

__device__ __forceinline__ void gld_lds16(const void* g, void* l) {
    __builtin_amdgcn_global_load_lds(
        (const __attribute__((address_space(1))) void*)g,
        (__attribute__((address_space(3))) void*)l,
        16, 0, 0);
}

// ---------- fp32 -> bf16 convert (vectorized) ----------
__global__ void cvt_f32_bf16(const float* __restrict__ in, bf16* __restrict__ out, int n) {
    int i = (blockIdx.x * blockDim.x + threadIdx.x) * 8;
    if (i >= n) return;
    f32x4 a = *(const f32x4*)(in + i);
    f32x4 b = *(const f32x4*)(in + i + 4);
    bf16x8 o;
#pragma unroll
    for (int j = 0; j < 4; ++j) { o[j] = (bf16)a[j]; o[j + 4] = (bf16)b[j]; }
    *(bf16x8*)(out + i) = o;
}

// ---------- transpose + convert: in[R][C] f32 -> out[C][R] bf16 ----------
__global__ void transpose_cvt(const float* __restrict__ in, bf16* __restrict__ out, int R, int C) {
    __shared__ float tile[32][33];
    int c0 = blockIdx.x * 32, r0 = blockIdx.y * 32;
    int tc = threadIdx.x & 31, tr = threadIdx.x >> 5; // tr in 0..7
#pragma unroll
    for (int i = 0; i < 4; ++i) {
        int r = tr + i * 8;
        tile[r][tc] = in[(size_t)(r0 + r) * C + c0 + tc];
    }
    __syncthreads();
#pragma unroll
    for (int i = 0; i < 4; ++i) {
        int r = tr + i * 8; // out row = original column
        out[(size_t)(c0 + r) * R + r0 + tc] = (bf16)tile[tc][r];
    }
}

// ---------- bf16 GEMM, C = A[M,K] @ Bt[N,K]^T ; 128x128 tile, BK=32, 4 waves ----------
template <int EPI>
__global__ void __launch_bounds__(256) gemm_bf16(
    const bf16* __restrict__ A, const bf16* __restrict__ Bt, int M, int N, int K,
    float* __restrict__ Cf, const float* __restrict__ bias,
    bf16* __restrict__ q_out, bf16* __restrict__ k_out, bf16* __restrict__ v_out)
{
    __shared__ bf16 As[128 * 32];
    __shared__ bf16 Bs[128 * 32];
    const int t = threadIdx.x, w = t >> 6, l = t & 63;
    const int l15 = l & 15, lh = l >> 4;
    const int m0 = blockIdx.y * 128, n0 = blockIdx.x * 128;
    const int wm = w >> 1, wn = w & 1;

    const int srow = w * 16 + (l >> 2);
    const int scol = (l & 3) * 8;
    const bf16* gA = A + (size_t)(m0 + srow) * K + scol;
    const bf16* gB = Bt + (size_t)(n0 + srow) * K + scol;
    char* lA = (char*)As + w * 1024;
    char* lB = (char*)Bs + w * 1024;

    f32x4 acc[4][4] = {};

    for (int kt = 0; kt < K; kt += 32) {
        __syncthreads();
        gld_lds16(gA + kt, lA);
        gld_lds16(gA + (size_t)64 * K + kt, lA + 4096);
        gld_lds16(gB + kt, lB);
        gld_lds16(gB + (size_t)64 * K + kt, lB + 4096);
        asm volatile("s_waitcnt vmcnt(0)" ::: "memory");
        __syncthreads();

        const bf16* pa = As + (wm * 64 + l15) * 32 + lh * 8;
        const bf16* pb = Bs + (wn * 64 + l15) * 32 + lh * 8;
        bf16x8 af[4], bfr[4];
#pragma unroll
        for (int i = 0; i < 4; ++i) {
            af[i]  = *(const bf16x8*)(pa + i * 512);
            bfr[i] = *(const bf16x8*)(pb + i * 512);
        }
#pragma unroll
        for (int mi = 0; mi < 4; ++mi)
#pragma unroll
            for (int ni = 0; ni < 4; ++ni)
                acc[mi][ni] = MFMA_16x16x32(af[mi], bfr[ni], acc[mi][ni]);
    }

    if (EPI == 1) {
#pragma unroll
        for (int ni = 0; ni < 4; ++ni) {
            int n = n0 + wn * 64 + ni * 16 + l15;
            float bb = bias[n];
#pragma unroll
            for (int mi = 0; mi < 4; ++mi)
#pragma unroll
                for (int r = 0; r < 4; ++r) {
                    int m = m0 + wm * 64 + mi * 16 + lh * 4 + r;
                    Cf[(size_t)m * N + n] = acc[mi][ni][r] + bb;
                }
        }
    } else {
        const int which = n0 >> 10; // 0:q 1:k 2:v — uniform per block
#pragma unroll
        for (int ni = 0; ni < 4; ++ni) {
            int n = n0 + wn * 64 + ni * 16 + l15;
            int h = (n >> 6) & 15;
            int d = n & 63;
#pragma unroll
            for (int mi = 0; mi < 4; ++mi)
#pragma unroll
                for (int r = 0; r < 4; ++r) {
                    int m = m0 + wm * 64 + mi * 16 + lh * 4 + r;
                    int b = m >> 11, tt = m & 2047;
                    bf16 val = (bf16)acc[mi][ni][r];
                    size_t hb = (size_t)b * 16 + h;
                    if (which == 0)      q_out[(hb * 2048 + tt) * 64 + d] = val;
                    else if (which == 1) k_out[(hb * 2048 + tt) * 64 + d] = val;
                    else                 v_out[(hb * 64 + d) * 2048 + tt] = val;
                }
        }
    }
}

// ---------- attention with head-axis softmax, v3 ----------
// QB=16 so register state fits 64 unified regs -> 2 blocks/CU (32 waves).
// grid 1024: bid&7 -> (b, kslice) so each XCD's L2 holds its 2MB K/V slice;
// bid>>3 -> qtile (128). 1024 threads = 16 waves, wave w = head w.
// exp2 applied in score phase (in-register); softmax phase only computes
// per-(q,k) column sums over heads -> invS; PV multiplies e*inv.
__global__ void __launch_bounds__(1024, 8) attn_kernel(
    const bf16* __restrict__ Q, const bf16* __restrict__ Kmat, const bf16* __restrict__ Vt,
    bf16* __restrict__ p0, bf16* __restrict__ p1, bf16* __restrict__ p2, bf16* __restrict__ p3)
{
    __shared__ bf16 S[16][16][40];  // exp2'd scores e[h][q][k], padded
    __shared__ bf16 invS[16][40];   // 1/sum_h e at each (q,k)
    const int t = threadIdx.x;
    const int w = t >> 6;       // head
    const int l = t & 63;
    const int l15 = l & 15, lh = l >> 4;

    const int bid = blockIdx.x;
    const int b = (bid & 7) >> 2;
    const int ks = bid & 3;
    const int qt = (bid >> 3) * 16;

    const size_t headQK = ((size_t)b * 16 + w) * (2048 * 64); // [B,H,T,HD]
    const size_t headV  = ((size_t)b * 16 + w) * (64 * 2048); // [B,H,HD,T]
    const float SCL = 0.125f * 1.44269504089f; // scale * log2(e)

    // Q fragments live in registers for the whole block (8 VGPRs)
    bf16x8 aq[2];
#pragma unroll
    for (int ds = 0; ds < 2; ++ds)
        aq[ds] = *(const bf16x8*)(Q + headQK + (size_t)(qt + l15) * 64 + ds * 32 + lh * 8);

    f32x4 o[4] = {};

    for (int it = 0; it < 16; ++it) {
        const int kt = ks * 512 + it * 32;
        __syncthreads(); // previous iteration's PV done reading S/invS
        // --- scores -> e = exp2(s*SCL), stored bf16 (softmax-over-heads numerator) ---
#pragma unroll
        for (int kb = 0; kb < 2; ++kb) {
            const bf16* kp = Kmat + headQK + (size_t)(kt + kb * 16 + l15) * 64 + lh * 8;
            bf16x8 bk0 = *(const bf16x8*)(kp);
            bf16x8 bk1 = *(const bf16x8*)(kp + 32);
            f32x4 s = {};
            s = MFMA_16x16x32(aq[0], bk0, s);
            s = MFMA_16x16x32(aq[1], bk1, s);
#pragma unroll
            for (int r = 0; r < 4; ++r)
                S[w][lh * 4 + r][kb * 16 + l15] = (bf16)exp2f(s[r] * SCL);
        }
        __syncthreads();
        // --- column sums over heads (512 columns; waves 0..7, one column each) ---
        if (t < 512) {
            const int sqi = t >> 5, ski = t & 31;
            float s0 = 0.f;
#pragma unroll
            for (int hh = 0; hh < 16; ++hh)
                s0 += (float)S[hh][sqi][ski];
            invS[sqi][ski] = (bf16)__builtin_amdgcn_rcpf(s0);
        }
        __syncthreads();
        // --- PV: o += (e * inv) @ V ---
        bf16x8 ev  = *(const bf16x8*)(&S[w][l15][lh * 8]);
        bf16x8 ivv = *(const bf16x8*)(&invS[l15][lh * 8]);
        bf16x8 ap;
#pragma unroll
        for (int j = 0; j < 8; ++j)
            ap[j] = (bf16)((float)ev[j] * (float)ivv[j]);
#pragma unroll
        for (int ni = 0; ni < 4; ++ni) {
            bf16x8 bv = *(const bf16x8*)(Vt + headV + (size_t)(ni * 16 + l15) * 2048 + kt + lh * 8);
            o[ni] = MFMA_16x16x32(ap, bv, o[ni]);
        }
    }
    // write this k-slice's partial: slice[ks] layout [b][t][h*64+d]
    bf16* dst = (ks == 0 ? p0 : ks == 1 ? p1 : ks == 2 ? p2 : p3) + (size_t)b * (2048 * 1024);
#pragma unroll
    for (int ni = 0; ni < 4; ++ni)
#pragma unroll
        for (int r = 0; r < 4; ++r) {
            int tt = qt + lh * 4 + r;
            int d = ni * 16 + l15;
            dst[(size_t)tt * 1024 + w * 64 + d] = (bf16)o[ni][r];
        }
}

// ---------- sum the four k-slice partials -> attn bf16 (in-place onto p0 region) ----------
__global__ void reduce_part4(const bf16* __restrict__ p0, const bf16* __restrict__ p1,
                             const bf16* __restrict__ p2, const bf16* __restrict__ p3,
                             bf16* __restrict__ out, int n) {
    int i = (blockIdx.x * blockDim.x + threadIdx.x) * 8;
    if (i >= n) return;
    bf16x8 a = *(const bf16x8*)(p0 + i);
    bf16x8 b = *(const bf16x8*)(p1 + i);
    bf16x8 c = *(const bf16x8*)(p2 + i);
    bf16x8 d = *(const bf16x8*)(p3 + i);
    bf16x8 o;
#pragma unroll
    for (int j = 0; j < 8; ++j)
        o[j] = (bf16)(((float)a[j] + (float)b[j]) + ((float)c[j] + (float)d[j]));
    *(bf16x8*)(out + i) = o;
}

extern "C" void kernel_launch(void* const* d_in, const int* in_sizes, int n_in,
                              void* d_out, int out_size, void* d_ws, size_t ws_size,
                              hipStream_t stream)
{
    const float* x      = (const float*)d_in[0];
    const float* w_qkv  = (const float*)d_in[1];
    const float* w_proj = (const float*)d_in[2];
    const float* b_proj = (const float*)d_in[3];
    float* out = (float*)d_out;

    // workspace layout (58 MiB; part slices overlap regions dead after gemm1)
    char* ws = (char*)d_ws;
    const size_t MB = 1048576;
    bf16* wprojT = (bf16*)(ws + 0 * MB);   //  2 MiB  w_proj^T bf16 [1024,1024]
    bf16* xb     = (bf16*)(ws + 2 * MB);   //  8 MiB  x bf16 [4096,1024]   (later: part0 / attnb)
    bf16* wqkvT  = (bf16*)(ws + 10 * MB);  //  6 MiB  w_qkv^T bf16 [3072,1024] (later: part1)
    bf16* qb     = (bf16*)(ws + 18 * MB);  //  8 MiB  Q  [B,H,T,HD]
    bf16* kb     = (bf16*)(ws + 26 * MB);  //  8 MiB  K  [B,H,T,HD]
    bf16* vt     = (bf16*)(ws + 34 * MB);  //  8 MiB  V^T[B,H,HD,T]
    bf16* part0  = (bf16*)(ws + 2 * MB);   //  8 MiB  (over xb, dead after gemm1)
    bf16* part1  = (bf16*)(ws + 10 * MB);  //  8 MiB  (over wqkvT)
    bf16* part2  = (bf16*)(ws + 42 * MB);  //  8 MiB
    bf16* part3  = (bf16*)(ws + 50 * MB);  //  8 MiB
    bf16* attnb  = (bf16*)(ws + 2 * MB);   //  8 MiB  = part0 (element-wise in-place reduce)

    cvt_f32_bf16<<<2048, 256, 0, stream>>>(x, xb, 4194304);
    transpose_cvt<<<dim3(96, 32), 256, 0, stream>>>(w_qkv, wqkvT, 1024, 3072);
    transpose_cvt<<<dim3(32, 32), 256, 0, stream>>>(w_proj, wprojT, 1024, 1024);

    // qkv projection: [4096,1024] @ [1024,3072] -> scatter to q/k/v^T
    gemm_bf16<0><<<dim3(24, 32), 256, 0, stream>>>(xb, wqkvT, 4096, 3072, 1024,
                                                   nullptr, nullptr, qb, kb, vt);
    // attention with head-axis softmax (4 k-slices, XCD-grouped, QB=16)
    attn_kernel<<<1024, 1024, 0, stream>>>(qb, kb, vt, part0, part1, part2, part3);
    reduce_part4<<<2048, 256, 0, stream>>>(part0, part1, part2, part3, attnb, 4194304);
    // output projection + bias -> fp32 d_out
    gemm_bf16<1><<<dim3(8, 32), 256, 0, stream>>>(attnb, wprojT, 4096, 1024, 1024,
                                                  out, b_proj, nullptr, nullptr, nullptr);

    (void)in_sizes; (void)n_in; (void)out_size; (void)ws_size;
}

// Round 4
// 228.379 us; speedup vs baseline: 1.6037x; 1.4413x over previous
//
#include <hip/hip_runtime.h>
#include <hip/hip_bf16.h>
#include <stdint.h>

// B=2, T=2048, D=1024, H=16, HD=64, SCALE=1/8. Softmax is over the HEAD axis.
typedef __bf16 bf16;
typedef __attribute__((ext_vector_type(8))) __bf16 bf16x8;
typedef __attribute__((ext_vector_type(4))) __bf16 bf16x4;
typedef __attribute__((ext_vector_type(4))) float f32x4;

#define MFMA_16x16x32(a, b, c) __builtin_amdgcn_mfma_f32_16x16x32_bf16((a), (b), (c), 0, 0, 0)

__device__ __forceinline__ void gld_lds16(const void* g, void* l) {
    __builtin_amdgcn_global_load_lds(
        (const __attribute__((address_space(1))) void*)g,
        (__attribute__((address_space(3))) void*)l,
        16, 0, 0);
}

// ---------- fp32 -> bf16 convert (vectorized) ----------
__global__ void cvt_f32_bf16(const float* __restrict__ in, bf16* __restrict__ out, int n) {
    int i = (blockIdx.x * blockDim.x + threadIdx.x) * 8;
    if (i >= n) return;
    f32x4 a = *(const f32x4*)(in + i);
    f32x4 b = *(const f32x4*)(in + i + 4);
    bf16x8 o;
#pragma unroll
    for (int j = 0; j < 4; ++j) { o[j] = (bf16)a[j]; o[j + 4] = (bf16)b[j]; }
    *(bf16x8*)(out + i) = o;
}

// ---------- transpose + convert: in[R][C] f32 -> out[C][R] bf16 ----------
__global__ void transpose_cvt(const float* __restrict__ in, bf16* __restrict__ out, int R, int C) {
    __shared__ float tile[32][33];
    int c0 = blockIdx.x * 32, r0 = blockIdx.y * 32;
    int tc = threadIdx.x & 31, tr = threadIdx.x >> 5; // tr in 0..7
#pragma unroll
    for (int i = 0; i < 4; ++i) {
        int r = tr + i * 8;
        tile[r][tc] = in[(size_t)(r0 + r) * C + c0 + tc];
    }
    __syncthreads();
#pragma unroll
    for (int i = 0; i < 4; ++i) {
        int r = tr + i * 8; // out row = original column
        out[(size_t)(c0 + r) * R + r0 + tc] = (bf16)tile[tc][r];
    }
}

// ---------- bf16 GEMM, C = A[M,K] @ Bt[N,K]^T ; 128x128 tile, BK=32, 4 waves ----------
template <int EPI>
__global__ void __launch_bounds__(256) gemm_bf16(
    const bf16* __restrict__ A, const bf16* __restrict__ Bt, int M, int N, int K,
    float* __restrict__ Cf, const float* __restrict__ bias,
    bf16* __restrict__ q_out, bf16* __restrict__ k_out, bf16* __restrict__ v_out)
{
    __shared__ bf16 As[128 * 32];
    __shared__ bf16 Bs[128 * 32];
    const int t = threadIdx.x, w = t >> 6, l = t & 63;
    const int l15 = l & 15, lh = l >> 4;
    const int m0 = blockIdx.y * 128, n0 = blockIdx.x * 128;
    const int wm = w >> 1, wn = w & 1;

    const int srow = w * 16 + (l >> 2);
    const int scol = (l & 3) * 8;
    const bf16* gA = A + (size_t)(m0 + srow) * K + scol;
    const bf16* gB = Bt + (size_t)(n0 + srow) * K + scol;
    char* lA = (char*)As + w * 1024;
    char* lB = (char*)Bs + w * 1024;

    f32x4 acc[4][4] = {};

    for (int kt = 0; kt < K; kt += 32) {
        __syncthreads();
        gld_lds16(gA + kt, lA);
        gld_lds16(gA + (size_t)64 * K + kt, lA + 4096);
        gld_lds16(gB + kt, lB);
        gld_lds16(gB + (size_t)64 * K + kt, lB + 4096);
        asm volatile("s_waitcnt vmcnt(0)" ::: "memory");
        __syncthreads();

        const bf16* pa = As + (wm * 64 + l15) * 32 + lh * 8;
        const bf16* pb = Bs + (wn * 64 + l15) * 32 + lh * 8;
        bf16x8 af[4], bfr[4];
#pragma unroll
        for (int i = 0; i < 4; ++i) {
            af[i]  = *(const bf16x8*)(pa + i * 512);
            bfr[i] = *(const bf16x8*)(pb + i * 512);
        }
#pragma unroll
        for (int mi = 0; mi < 4; ++mi)
#pragma unroll
            for (int ni = 0; ni < 4; ++ni)
                acc[mi][ni] = MFMA_16x16x32(af[mi], bfr[ni], acc[mi][ni]);
    }

    if (EPI == 1) {
#pragma unroll
        for (int ni = 0; ni < 4; ++ni) {
            int n = n0 + wn * 64 + ni * 16 + l15;
            float bb = bias[n];
#pragma unroll
            for (int mi = 0; mi < 4; ++mi)
#pragma unroll
                for (int r = 0; r < 4; ++r) {
                    int m = m0 + wm * 64 + mi * 16 + lh * 4 + r;
                    Cf[(size_t)m * N + n] = acc[mi][ni][r] + bb;
                }
        }
    } else {
        const int which = n0 >> 10; // 0:q 1:k 2:v — uniform per block
#pragma unroll
        for (int ni = 0; ni < 4; ++ni) {
            int n = n0 + wn * 64 + ni * 16 + l15;
            int h = (n >> 6) & 15;
            int d = n & 63;
#pragma unroll
            for (int mi = 0; mi < 4; ++mi)
#pragma unroll
                for (int r = 0; r < 4; ++r) {
                    int m = m0 + wm * 64 + mi * 16 + lh * 4 + r;
                    int b = m >> 11, tt = m & 2047;
                    bf16 val = (bf16)acc[mi][ni][r];
                    size_t hb = (size_t)b * 16 + h;
                    if (which == 0)      q_out[(hb * 2048 + tt) * 64 + d] = val;
                    else if (which == 1) k_out[(hb * 2048 + tt) * 64 + d] = val;
                    else                 v_out[(hb * 64 + d) * 2048 + tt] = val;
                }
        }
    }
}

// ---------- attention with head-axis softmax, v4 ----------
// QB=32, KB=64 -> 8 barrier-generations per block. Swapped score MFMA
// (mfma(K,Q)) so each lane holds 4 consecutive k at fixed q: exp'd scores
// pack into ONE ds_write_b64; S layout [h][q][k+pad88] keeps PV A-frag reads
// b128 (k-contiguous) and head-sum reads b64. 16 waves = 16 heads.
// grid 512: bid&7 -> (b,ks) XCD-pinned (1MB K + 1MB V slice per XCD L2).
__global__ void __launch_bounds__(1024, 4) attn_kernel(
    const bf16* __restrict__ Q, const bf16* __restrict__ Kmat, const bf16* __restrict__ Vt,
    bf16* __restrict__ p0, bf16* __restrict__ p1, bf16* __restrict__ p2, bf16* __restrict__ p3)
{
    __shared__ bf16 S[16][32][88];   // exp2'd scores e[h][q][k], pad 88 (176B rows: 16B-aligned, ~2-way banks)
    __shared__ bf16 invS[32][88];    // 1/sum_h e at each (q,k)
    const int t = threadIdx.x;
    const int w = t >> 6;       // head
    const int l = t & 63;
    const int l15 = l & 15, lh = l >> 4;

    const int bid = blockIdx.x;
    const int b = (bid & 7) >> 2;
    const int ks = bid & 3;
    const int qt = (bid >> 3) * 32;

    const size_t headQK = ((size_t)b * 16 + w) * (2048 * 64); // [B,H,T,HD]
    const size_t headV  = ((size_t)b * 16 + w) * (64 * 2048); // [B,H,HD,T]
    const float SCL = 0.125f * 1.44269504089f; // scale * log2(e)

    // Q fragments (B-operand of swapped score MFMA; also fixed for whole block)
    bf16x8 qf[2][2];
#pragma unroll
    for (int qb2 = 0; qb2 < 2; ++qb2)
#pragma unroll
        for (int dc = 0; dc < 2; ++dc)
            qf[qb2][dc] = *(const bf16x8*)(Q + headQK + (size_t)(qt + qb2 * 16 + l15) * 64 + dc * 32 + lh * 8);

    f32x4 o[2][4] = {};

    for (int it = 0; it < 8; ++it) {
        const int kt = ks * 512 + it * 64;
        __syncthreads(); // previous generation's PV done reading S/invS
        // --- scores (swapped): D[k][q]; lane holds k=kb*16+4*lh+r, q=qb2*16+l15 ---
#pragma unroll
        for (int kb = 0; kb < 4; ++kb) {
            const bf16* kp = Kmat + headQK + (size_t)(kt + kb * 16 + l15) * 64 + lh * 8;
            bf16x8 ak0 = *(const bf16x8*)(kp);
            bf16x8 ak1 = *(const bf16x8*)(kp + 32);
#pragma unroll
            for (int qb2 = 0; qb2 < 2; ++qb2) {
                f32x4 s = {};
                s = MFMA_16x16x32(ak0, qf[qb2][0], s);
                s = MFMA_16x16x32(ak1, qf[qb2][1], s);
                bf16x4 pk;
#pragma unroll
                for (int r = 0; r < 4; ++r)
                    pk[r] = (bf16)exp2f(s[r] * SCL);
                *(bf16x4*)&S[w][qb2 * 16 + l15][kb * 16 + lh * 4] = pk; // one b64
            }
        }
        __syncthreads();
        // --- prefetch V (ksub=0) while the sum phase runs ---
        bf16x8 bv0[4];
#pragma unroll
        for (int ni = 0; ni < 4; ++ni)
            bv0[ni] = *(const bf16x8*)(Vt + headV + (size_t)(ni * 16 + l15) * 2048 + kt + lh * 8);
        // --- column sums over heads: thread owns a k-quad at one q (b64 reads) ---
        if (t < 512) {
            const int sq = t >> 4, kq = (t & 15) * 4;
            float a0 = 0.f, a1 = 0.f, a2 = 0.f, a3 = 0.f;
#pragma unroll
            for (int hh = 0; hh < 16; ++hh) {
                bf16x4 e4 = *(const bf16x4*)&S[hh][sq][kq];
                a0 += (float)e4[0]; a1 += (float)e4[1];
                a2 += (float)e4[2]; a3 += (float)e4[3];
            }
            bf16x4 iv;
            iv[0] = (bf16)__builtin_amdgcn_rcpf(a0);
            iv[1] = (bf16)__builtin_amdgcn_rcpf(a1);
            iv[2] = (bf16)__builtin_amdgcn_rcpf(a2);
            iv[3] = (bf16)__builtin_amdgcn_rcpf(a3);
            *(bf16x4*)&invS[sq][kq] = iv;
        }
        __syncthreads();
        // --- PV: o += (e * inv) @ V over the two k=32 subtiles ---
#pragma unroll
        for (int ksub = 0; ksub < 2; ++ksub) {
            bf16x8 bv[4];
#pragma unroll
            for (int ni = 0; ni < 4; ++ni) {
                if (ksub == 0) bv[ni] = bv0[ni];
                else bv[ni] = *(const bf16x8*)(Vt + headV + (size_t)(ni * 16 + l15) * 2048 + kt + 32 + lh * 8);
            }
#pragma unroll
            for (int qb2 = 0; qb2 < 2; ++qb2) {
                bf16x8 ev  = *(const bf16x8*)(&S[w][qb2 * 16 + l15][ksub * 32 + lh * 8]);
                bf16x8 ivv = *(const bf16x8*)(&invS[qb2 * 16 + l15][ksub * 32 + lh * 8]);
                bf16x8 ap;
#pragma unroll
                for (int j = 0; j < 8; ++j)
                    ap[j] = (bf16)((float)ev[j] * (float)ivv[j]);
#pragma unroll
                for (int ni = 0; ni < 4; ++ni)
                    o[qb2][ni] = MFMA_16x16x32(ap, bv[ni], o[qb2][ni]);
            }
        }
    }
    // write this k-slice's partial: slice[ks] layout [b][t][h*64+d]
    bf16* dst = (ks == 0 ? p0 : ks == 1 ? p1 : ks == 2 ? p2 : p3) + (size_t)b * (2048 * 1024);
#pragma unroll
    for (int qb2 = 0; qb2 < 2; ++qb2)
#pragma unroll
        for (int ni = 0; ni < 4; ++ni)
#pragma unroll
            for (int r = 0; r < 4; ++r) {
                int tt = qt + qb2 * 16 + lh * 4 + r;
                int d = ni * 16 + l15;
                dst[(size_t)tt * 1024 + w * 64 + d] = (bf16)o[qb2][ni][r];
            }
}

// ---------- sum the four k-slice partials -> attn bf16 ----------
__global__ void reduce_part4(const bf16* __restrict__ p0, const bf16* __restrict__ p1,
                             const bf16* __restrict__ p2, const bf16* __restrict__ p3,
                             bf16* __restrict__ out, int n) {
    int i = (blockIdx.x * blockDim.x + threadIdx.x) * 8;
    if (i >= n) return;
    bf16x8 a = *(const bf16x8*)(p0 + i);
    bf16x8 b = *(const bf16x8*)(p1 + i);
    bf16x8 c = *(const bf16x8*)(p2 + i);
    bf16x8 d = *(const bf16x8*)(p3 + i);
    bf16x8 o;
#pragma unroll
    for (int j = 0; j < 8; ++j)
        o[j] = (bf16)(((float)a[j] + (float)b[j]) + ((float)c[j] + (float)d[j]));
    *(bf16x8*)(out + i) = o;
}

extern "C" void kernel_launch(void* const* d_in, const int* in_sizes, int n_in,
                              void* d_out, int out_size, void* d_ws, size_t ws_size,
                              hipStream_t stream)
{
    const float* x      = (const float*)d_in[0];
    const float* w_qkv  = (const float*)d_in[1];
    const float* w_proj = (const float*)d_in[2];
    const float* b_proj = (const float*)d_in[3];
    float* out = (float*)d_out;

    // workspace layout (58 MiB; part slices overlap regions dead after gemm1)
    char* ws = (char*)d_ws;
    const size_t MB = 1048576;
    bf16* wprojT = (bf16*)(ws + 0 * MB);   //  2 MiB  w_proj^T bf16 [1024,1024]
    bf16* xb     = (bf16*)(ws + 2 * MB);   //  8 MiB  x bf16 [4096,1024]   (later: part0 / attnb)
    bf16* wqkvT  = (bf16*)(ws + 10 * MB);  //  6 MiB  w_qkv^T bf16 [3072,1024] (later: part1)
    bf16* qb     = (bf16*)(ws + 18 * MB);  //  8 MiB  Q  [B,H,T,HD]
    bf16* kb     = (bf16*)(ws + 26 * MB);  //  8 MiB  K  [B,H,T,HD]
    bf16* vt     = (bf16*)(ws + 34 * MB);  //  8 MiB  V^T[B,H,HD,T]
    bf16* part0  = (bf16*)(ws + 2 * MB);   //  8 MiB  (over xb, dead after gemm1)
    bf16* part1  = (bf16*)(ws + 10 * MB);  //  8 MiB  (over wqkvT)
    bf16* part2  = (bf16*)(ws + 42 * MB);  //  8 MiB
    bf16* part3  = (bf16*)(ws + 50 * MB);  //  8 MiB
    bf16* attnb  = (bf16*)(ws + 2 * MB);   //  8 MiB  = part0 (element-wise in-place reduce)

    cvt_f32_bf16<<<2048, 256, 0, stream>>>(x, xb, 4194304);
    transpose_cvt<<<dim3(96, 32), 256, 0, stream>>>(w_qkv, wqkvT, 1024, 3072);
    transpose_cvt<<<dim3(32, 32), 256, 0, stream>>>(w_proj, wprojT, 1024, 1024);

    // qkv projection: [4096,1024] @ [1024,3072] -> scatter to q/k/v^T
    gemm_bf16<0><<<dim3(24, 32), 256, 0, stream>>>(xb, wqkvT, 4096, 3072, 1024,
                                                   nullptr, nullptr, qb, kb, vt);
    // attention with head-axis softmax (QB=32, KB=64, 4 k-slices XCD-pinned)
    attn_kernel<<<512, 1024, 0, stream>>>(qb, kb, vt, part0, part1, part2, part3);
    reduce_part4<<<2048, 256, 0, stream>>>(part0, part1, part2, part3, attnb, 4194304);
    // output projection + bias -> fp32 d_out
    gemm_bf16<1><<<dim3(8, 32), 256, 0, stream>>>(attnb, wprojT, 4096, 1024, 1024,
                                                  out, b_proj, nullptr, nullptr, nullptr);

    (void)in_sizes; (void)n_in; (void)out_size; (void)ws_size;
}

// Round 5
// 228.336 us; speedup vs baseline: 1.6040x; 1.0002x over previous
//
#include <hip/hip_runtime.h>
#include <hip/hip_bf16.h>
#include <stdint.h>

// B=2, T=2048, D=1024, H=16, HD=64, SCALE=1/8. Softmax is over the HEAD axis.
typedef __bf16 bf16;
typedef __attribute__((ext_vector_type(8))) __bf16 bf16x8;
typedef __attribute__((ext_vector_type(4))) __bf16 bf16x4;
typedef __attribute__((ext_vector_type(4))) float f32x4;

#define MFMA_16x16x32(a, b, c) __builtin_amdgcn_mfma_f32_16x16x32_bf16((a), (b), (c), 0, 0, 0)

__device__ __forceinline__ void gld_lds16(const void* g, void* l) {
    __builtin_amdgcn_global_load_lds(
        (const __attribute__((address_space(1))) void*)g,
        (__attribute__((address_space(3))) void*)l,
        16, 0, 0);
}

// ---------- fp32 -> bf16 convert (vectorized) ----------
__global__ void cvt_f32_bf16(const float* __restrict__ in, bf16* __restrict__ out, int n) {
    int i = (blockIdx.x * blockDim.x + threadIdx.x) * 8;
    if (i >= n) return;
    f32x4 a = *(const f32x4*)(in + i);
    f32x4 b = *(const f32x4*)(in + i + 4);
    bf16x8 o;
#pragma unroll
    for (int j = 0; j < 4; ++j) { o[j] = (bf16)a[j]; o[j + 4] = (bf16)b[j]; }
    *(bf16x8*)(out + i) = o;
}

// ---------- transpose + convert: in[R][C] f32 -> out[C][R] bf16 ----------
__global__ void transpose_cvt(const float* __restrict__ in, bf16* __restrict__ out, int R, int C) {
    __shared__ float tile[32][33];
    int c0 = blockIdx.x * 32, r0 = blockIdx.y * 32;
    int tc = threadIdx.x & 31, tr = threadIdx.x >> 5; // tr in 0..7
#pragma unroll
    for (int i = 0; i < 4; ++i) {
        int r = tr + i * 8;
        tile[r][tc] = in[(size_t)(r0 + r) * C + c0 + tc];
    }
    __syncthreads();
#pragma unroll
    for (int i = 0; i < 4; ++i) {
        int r = tr + i * 8; // out row = original column
        out[(size_t)(c0 + r) * R + r0 + tc] = (bf16)tile[tc][r];
    }
}

// ---------- bf16 GEMM, C = A[M,K] @ Bt[N,K]^T ; 128x128 tile, BK=32, 4 waves ----------
template <int EPI>
__global__ void __launch_bounds__(256) gemm_bf16(
    const bf16* __restrict__ A, const bf16* __restrict__ Bt, int M, int N, int K,
    float* __restrict__ Cf, const float* __restrict__ bias,
    bf16* __restrict__ q_out, bf16* __restrict__ k_out, bf16* __restrict__ v_out)
{
    __shared__ bf16 As[128 * 32];
    __shared__ bf16 Bs[128 * 32];
    const int t = threadIdx.x, w = t >> 6, l = t & 63;
    const int l15 = l & 15, lh = l >> 4;
    const int m0 = blockIdx.y * 128, n0 = blockIdx.x * 128;
    const int wm = w >> 1, wn = w & 1;

    const int srow = w * 16 + (l >> 2);
    const int scol = (l & 3) * 8;
    const bf16* gA = A + (size_t)(m0 + srow) * K + scol;
    const bf16* gB = Bt + (size_t)(n0 + srow) * K + scol;
    char* lA = (char*)As + w * 1024;
    char* lB = (char*)Bs + w * 1024;

    f32x4 acc[4][4] = {};

    for (int kt = 0; kt < K; kt += 32) {
        __syncthreads();
        gld_lds16(gA + kt, lA);
        gld_lds16(gA + (size_t)64 * K + kt, lA + 4096);
        gld_lds16(gB + kt, lB);
        gld_lds16(gB + (size_t)64 * K + kt, lB + 4096);
        asm volatile("s_waitcnt vmcnt(0)" ::: "memory");
        __syncthreads();

        const bf16* pa = As + (wm * 64 + l15) * 32 + lh * 8;
        const bf16* pb = Bs + (wn * 64 + l15) * 32 + lh * 8;
        bf16x8 af[4], bfr[4];
#pragma unroll
        for (int i = 0; i < 4; ++i) {
            af[i]  = *(const bf16x8*)(pa + i * 512);
            bfr[i] = *(const bf16x8*)(pb + i * 512);
        }
#pragma unroll
        for (int mi = 0; mi < 4; ++mi)
#pragma unroll
            for (int ni = 0; ni < 4; ++ni)
                acc[mi][ni] = MFMA_16x16x32(af[mi], bfr[ni], acc[mi][ni]);
    }

    if (EPI == 1) {
#pragma unroll
        for (int ni = 0; ni < 4; ++ni) {
            int n = n0 + wn * 64 + ni * 16 + l15;
            float bb = bias[n];
#pragma unroll
            for (int mi = 0; mi < 4; ++mi)
#pragma unroll
                for (int r = 0; r < 4; ++r) {
                    int m = m0 + wm * 64 + mi * 16 + lh * 4 + r;
                    Cf[(size_t)m * N + n] = acc[mi][ni][r] + bb;
                }
        }
    } else {
        const int which = n0 >> 10; // 0:q 1:k 2:v — uniform per block
#pragma unroll
        for (int ni = 0; ni < 4; ++ni) {
            int n = n0 + wn * 64 + ni * 16 + l15;
            int h = (n >> 6) & 15;
            int d = n & 63;
#pragma unroll
            for (int mi = 0; mi < 4; ++mi)
#pragma unroll
                for (int r = 0; r < 4; ++r) {
                    int m = m0 + wm * 64 + mi * 16 + lh * 4 + r;
                    int b = m >> 11, tt = m & 2047;
                    bf16 val = (bf16)acc[mi][ni][r];
                    size_t hb = (size_t)b * 16 + h;
                    if (which == 0)      q_out[(hb * 2048 + tt) * 64 + d] = val;
                    else if (which == 1) k_out[(hb * 2048 + tt) * 64 + d] = val;
                    else                 v_out[(hb * 64 + d) * 2048 + tt] = val;
                }
        }
    }
}

// ---------- attention with head-axis softmax, v5 ----------
// QB=32, KB=128 -> 4 barrier-generations per block (2048 total, 8/CU).
// Swapped score MFMA (mfma(K,Q)): lane holds 4 consecutive k at fixed q ->
// exp'd scores pack into ONE ds_write_b64. S[h][q][k+pad136] keeps PV A-frag
// reads b128 (k-contiguous); head-sum phase uses ALL 16 waves (4096 columns,
// one k-quad per thread, b64 reads). grid 512: bid&7 -> (b,ks) XCD-pinned.
__global__ void __launch_bounds__(1024, 4) attn_kernel(
    const bf16* __restrict__ Q, const bf16* __restrict__ Kmat, const bf16* __restrict__ Vt,
    bf16* __restrict__ p0, bf16* __restrict__ p1, bf16* __restrict__ p2, bf16* __restrict__ p3)
{
    __shared__ bf16 S[16][32][136];  // exp2'd scores e[h][q][k]; 272B rows: 16B-aligned, ~2-way banks
    __shared__ bf16 invS[32][136];   // 1/sum_h e at each (q,k)
    const int t = threadIdx.x;
    const int w = t >> 6;       // head
    const int l = t & 63;
    const int l15 = l & 15, lh = l >> 4;

    const int bid = blockIdx.x;
    const int b = (bid & 7) >> 2;
    const int ks = bid & 3;
    const int qt = (bid >> 3) * 32;

    const size_t headQK = ((size_t)b * 16 + w) * (2048 * 64); // [B,H,T,HD]
    const size_t headV  = ((size_t)b * 16 + w) * (64 * 2048); // [B,H,HD,T]
    const float SCL = 0.125f * 1.44269504089f; // scale * log2(e)

    // Q fragments (B-operand of swapped score MFMA; fixed for whole block)
    bf16x8 qf[2][2];
#pragma unroll
    for (int qb2 = 0; qb2 < 2; ++qb2)
#pragma unroll
        for (int dc = 0; dc < 2; ++dc)
            qf[qb2][dc] = *(const bf16x8*)(Q + headQK + (size_t)(qt + qb2 * 16 + l15) * 64 + dc * 32 + lh * 8);

    f32x4 o[2][4] = {};

    for (int it = 0; it < 4; ++it) {
        const int kt = ks * 512 + it * 128;
        __syncthreads(); // previous generation's PV done reading S/invS
        // --- scores (swapped): lane holds k=kb*16+4*lh+r, q=qb2*16+l15 ---
#pragma unroll
        for (int kb = 0; kb < 8; ++kb) {
            const bf16* kp = Kmat + headQK + (size_t)(kt + kb * 16 + l15) * 64 + lh * 8;
            bf16x8 ak0 = *(const bf16x8*)(kp);
            bf16x8 ak1 = *(const bf16x8*)(kp + 32);
#pragma unroll
            for (int qb2 = 0; qb2 < 2; ++qb2) {
                f32x4 s = {};
                s = MFMA_16x16x32(ak0, qf[qb2][0], s);
                s = MFMA_16x16x32(ak1, qf[qb2][1], s);
                bf16x4 pk;
#pragma unroll
                for (int r = 0; r < 4; ++r)
                    pk[r] = (bf16)exp2f(s[r] * SCL);
                *(bf16x4*)&S[w][qb2 * 16 + l15][kb * 16 + lh * 4] = pk; // one b64
            }
        }
        __syncthreads();
        // --- column sums over heads: ALL threads; one k-quad at one q each ---
        {
            const int sq = t >> 5, kq = (t & 31) * 4;
            float a0 = 0.f, a1 = 0.f, a2 = 0.f, a3 = 0.f;
#pragma unroll
            for (int hh = 0; hh < 16; ++hh) {
                bf16x4 e4 = *(const bf16x4*)&S[hh][sq][kq];
                a0 += (float)e4[0]; a1 += (float)e4[1];
                a2 += (float)e4[2]; a3 += (float)e4[3];
            }
            bf16x4 iv;
            iv[0] = (bf16)__builtin_amdgcn_rcpf(a0);
            iv[1] = (bf16)__builtin_amdgcn_rcpf(a1);
            iv[2] = (bf16)__builtin_amdgcn_rcpf(a2);
            iv[3] = (bf16)__builtin_amdgcn_rcpf(a3);
            *(bf16x4*)&invS[sq][kq] = iv;
        }
        __syncthreads();
        // --- PV: o += (e * inv) @ V over four k=32 subtiles ---
#pragma unroll
        for (int ksub = 0; ksub < 4; ++ksub) {
            bf16x8 bv[4];
#pragma unroll
            for (int ni = 0; ni < 4; ++ni)
                bv[ni] = *(const bf16x8*)(Vt + headV + (size_t)(ni * 16 + l15) * 2048 + kt + ksub * 32 + lh * 8);
#pragma unroll
            for (int qb2 = 0; qb2 < 2; ++qb2) {
                bf16x8 ev  = *(const bf16x8*)(&S[w][qb2 * 16 + l15][ksub * 32 + lh * 8]);
                bf16x8 ivv = *(const bf16x8*)(&invS[qb2 * 16 + l15][ksub * 32 + lh * 8]);
                bf16x8 ap;
#pragma unroll
                for (int j = 0; j < 8; ++j)
                    ap[j] = (bf16)((float)ev[j] * (float)ivv[j]);
#pragma unroll
                for (int ni = 0; ni < 4; ++ni)
                    o[qb2][ni] = MFMA_16x16x32(ap, bv[ni], o[qb2][ni]);
            }
        }
    }
    // write this k-slice's partial: slice[ks] layout [b][t][h*64+d]
    bf16* dst = (ks == 0 ? p0 : ks == 1 ? p1 : ks == 2 ? p2 : p3) + (size_t)b * (2048 * 1024);
#pragma unroll
    for (int qb2 = 0; qb2 < 2; ++qb2)
#pragma unroll
        for (int ni = 0; ni < 4; ++ni)
#pragma unroll
            for (int r = 0; r < 4; ++r) {
                int tt = qt + qb2 * 16 + lh * 4 + r;
                int d = ni * 16 + l15;
                dst[(size_t)tt * 1024 + w * 64 + d] = (bf16)o[qb2][ni][r];
            }
}

// ---------- sum the four k-slice partials -> attn bf16 ----------
__global__ void reduce_part4(const bf16* __restrict__ p0, const bf16* __restrict__ p1,
                             const bf16* __restrict__ p2, const bf16* __restrict__ p3,
                             bf16* __restrict__ out, int n) {
    int i = (blockIdx.x * blockDim.x + threadIdx.x) * 8;
    if (i >= n) return;
    bf16x8 a = *(const bf16x8*)(p0 + i);
    bf16x8 b = *(const bf16x8*)(p1 + i);
    bf16x8 c = *(const bf16x8*)(p2 + i);
    bf16x8 d = *(const bf16x8*)(p3 + i);
    bf16x8 o;
#pragma unroll
    for (int j = 0; j < 8; ++j)
        o[j] = (bf16)(((float)a[j] + (float)b[j]) + ((float)c[j] + (float)d[j]));
    *(bf16x8*)(out + i) = o;
}

extern "C" void kernel_launch(void* const* d_in, const int* in_sizes, int n_in,
                              void* d_out, int out_size, void* d_ws, size_t ws_size,
                              hipStream_t stream)
{
    const float* x      = (const float*)d_in[0];
    const float* w_qkv  = (const float*)d_in[1];
    const float* w_proj = (const float*)d_in[2];
    const float* b_proj = (const float*)d_in[3];
    float* out = (float*)d_out;

    // workspace layout (58 MiB; part slices overlap regions dead after gemm1)
    char* ws = (char*)d_ws;
    const size_t MB = 1048576;
    bf16* wprojT = (bf16*)(ws + 0 * MB);   //  2 MiB  w_proj^T bf16 [1024,1024]
    bf16* xb     = (bf16*)(ws + 2 * MB);   //  8 MiB  x bf16 [4096,1024]   (later: part0 / attnb)
    bf16* wqkvT  = (bf16*)(ws + 10 * MB);  //  6 MiB  w_qkv^T bf16 [3072,1024] (later: part1)
    bf16* qb     = (bf16*)(ws + 18 * MB);  //  8 MiB  Q  [B,H,T,HD]
    bf16* kb     = (bf16*)(ws + 26 * MB);  //  8 MiB  K  [B,H,T,HD]
    bf16* vt     = (bf16*)(ws + 34 * MB);  //  8 MiB  V^T[B,H,HD,T]
    bf16* part0  = (bf16*)(ws + 2 * MB);   //  8 MiB  (over xb, dead after gemm1)
    bf16* part1  = (bf16*)(ws + 10 * MB);  //  8 MiB  (over wqkvT)
    bf16* part2  = (bf16*)(ws + 42 * MB);  //  8 MiB
    bf16* part3  = (bf16*)(ws + 50 * MB);  //  8 MiB
    bf16* attnb  = (bf16*)(ws + 2 * MB);   //  8 MiB  = part0 (element-wise in-place reduce)

    cvt_f32_bf16<<<2048, 256, 0, stream>>>(x, xb, 4194304);
    transpose_cvt<<<dim3(96, 32), 256, 0, stream>>>(w_qkv, wqkvT, 1024, 3072);
    transpose_cvt<<<dim3(32, 32), 256, 0, stream>>>(w_proj, wprojT, 1024, 1024);

    // qkv projection: [4096,1024] @ [1024,3072] -> scatter to q/k/v^T
    gemm_bf16<0><<<dim3(24, 32), 256, 0, stream>>>(xb, wqkvT, 4096, 3072, 1024,
                                                   nullptr, nullptr, qb, kb, vt);
    // attention with head-axis softmax (QB=32, KB=128, 4 k-slices XCD-pinned)
    attn_kernel<<<512, 1024, 0, stream>>>(qb, kb, vt, part0, part1, part2, part3);
    reduce_part4<<<2048, 256, 0, stream>>>(part0, part1, part2, part3, attnb, 4194304);
    // output projection + bias -> fp32 d_out
    gemm_bf16<1><<<dim3(8, 32), 256, 0, stream>>>(attnb, wprojT, 4096, 1024, 1024,
                                                  out, b_proj, nullptr, nullptr, nullptr);

    (void)in_sizes; (void)n_in; (void)out_size; (void)ws_size;
}